// Round 13
// baseline (205.818 us; speedup 1.0000x reference)
//
#include <hip/hip_runtime.h>
#include <hip/hip_bf16.h>
#include <math.h>

#define KCOMP 32
#define DDIM  128
#define NPTS  65536
#define GMM_EPS 1e-6f
#define SA 129   // LDS row stride (odd -> conflict-free for scalar col access)
#define UFT 1280 // uint4 per component: 20 nonzero (db,kc) tiles * 64 lanes

typedef __attribute__((ext_vector_type(8)))  __bf16 bf16x8;
typedef __attribute__((ext_vector_type(16))) float  f32x16;

__device__ __forceinline__ unsigned short f2bf(float f){
  unsigned u = __builtin_bit_cast(unsigned, f);
  u = (u + 0x7FFFu + ((u >> 16) & 1u)) >> 16;   // RNE
  return (unsigned short)u;
}
__device__ __forceinline__ float rlane(float v, int lsrc){
  return __builtin_bit_cast(float, __builtin_amdgcn_readlane(__builtin_bit_cast(int, v), lsrc));
}

// ---------------------------------------------------------------------------
// chol_inv32 (R6, validated): register Cholesky + triangular inverse, 32x32.
// ---------------------------------------------------------------------------
__device__ __noinline__ float chol_inv32(float* __restrict__ Ab,
                                         float* __restrict__ Wb,
                                         const int c){
  float ar[32], lr[32], rd[32], s[32];
  #pragma unroll
  for(int i=0;i<32;i++) ar[i] = Ab[i*SA + c];
  float mydiag = 1.f;
  #pragma unroll
  for(int j=0;j<32;j++){
    float d   = rlane(ar[j], j);
    float rsd = rsqrtf(d);
    rd[j] = rsd;
    float Lcj  = ar[j]*rsd;
    lr[j] = (c>=j) ? Lcj : 0.f;
    if(c==j) mydiag = Lcj;
    float coef = Lcj*rsd;
    #pragma unroll
    for(int i=j+1;i<32;i++){
      float bij = rlane(ar[i], j);
      ar[i] = fmaf(-bij, coef, ar[i]);
    }
  }
  #pragma unroll
  for(int j=0;j<32;j++) Ab[c*SA + j] = lr[j];
  #pragma unroll
  for(int i=0;i<32;i++) s[i] = (i==c) ? 1.f : 0.f;
  #pragma unroll
  for(int j=0;j<32;j++){
    float vj = s[j]*rd[j];
    s[j] = vj;
    #pragma unroll
    for(int i=j+1;i<32;i++)
      s[i] = fmaf(-rlane(lr[j], i), vj, s[i]);
  }
  #pragma unroll
  for(int i=0;i<32;i++) Wb[i*SA + c] = s[i];
  return logf(mydiag);
}

// ---- GEMM unit bodies (noinline, validated R7-R11) ----
__device__ __noinline__ void panel_unit(float* __restrict__ A, const float* __restrict__ W,
                                        int r0, int c0, int b, int ibl){
  const int b32=b*32;
  float acc[4][4]={};
  for(int kc=0;kc<32;kc+=4){
    float a_[4][4], b_[4][4];
    #pragma unroll
    for(int e=0;e<4;e++)
      #pragma unroll
      for(int g=0;g<4;g++){
        a_[e][g]=A[(32*ibl+r0+e)*SA + b32+kc+g];
        b_[e][g]=W[(b32+c0+e)*SA   + b32+kc+g];
      }
    #pragma unroll
    for(int e=0;e<4;e++)
      #pragma unroll
      for(int f=0;f<4;f++)
        acc[e][f]+=a_[e][0]*b_[f][0]+a_[e][1]*b_[f][1]
                  +a_[e][2]*b_[f][2]+a_[e][3]*b_[f][3];
  }
  #pragma unroll
  for(int e=0;e<4;e++)
    #pragma unroll
    for(int f=0;f<4;f++)
      A[(32*ibl+r0+e)*SA + b32+c0+f] = acc[e][f];
}

__device__ __noinline__ void syrk_unit(float* __restrict__ A,
                                       int r0, int c0, int b, int ui, int uj){
  const int b32=b*32;
  float acc[4][4]={};
  for(int kc=0;kc<32;kc+=4){
    float a_[4][4], b_[4][4];
    #pragma unroll
    for(int e=0;e<4;e++)
      #pragma unroll
      for(int g=0;g<4;g++){
        a_[e][g]=A[(32*ui+r0+e)*SA + b32+kc+g];
        b_[e][g]=A[(32*uj+c0+e)*SA + b32+kc+g];
      }
    #pragma unroll
    for(int e=0;e<4;e++)
      #pragma unroll
      for(int f=0;f<4;f++)
        acc[e][f]+=a_[e][0]*b_[f][0]+a_[e][1]*b_[f][1]
                  +a_[e][2]*b_[f][2]+a_[e][3]*b_[f][3];
  }
  #pragma unroll
  for(int e=0;e<4;e++)
    #pragma unroll
    for(int f=0;f<4;f++)
      A[(32*ui+r0+e)*SA+32*uj+c0+f] -= acc[e][f];
}

__device__ __noinline__ void tg_unit(const float* __restrict__ A, const float* __restrict__ W,
                                     float* __restrict__ T, int r0, int c0, int i, int j){
  float acc[4][4]={};
  #pragma unroll 1
  for(int p=j;p<i;p++){
    for(int kc=0;kc<32;kc+=4){
      float a_[4][4], b_[4][4];
      #pragma unroll
      for(int e=0;e<4;e++)
        #pragma unroll
        for(int g=0;g<4;g++){
          a_[e][g]=A[(32*i+r0+e)*SA + 32*p+kc+g];
          b_[e][g]=W[(32*p+kc+e)*SA + 32*j+c0+g];
        }
      #pragma unroll
      for(int e=0;e<4;e++)
        #pragma unroll
        for(int f=0;f<4;f++)
          acc[e][f]+=a_[e][0]*b_[0][f]+a_[e][1]*b_[1][f]
                    +a_[e][2]*b_[2][f]+a_[e][3]*b_[3][f];
    }
  }
  #pragma unroll
  for(int e=0;e<4;e++)
    #pragma unroll
    for(int f=0;f<4;f++)
      T[(r0+e)*33+c0+f]=acc[e][f];
}

__device__ __noinline__ void a2_unit(float* __restrict__ W, const float* __restrict__ T,
                                     int r0, int c0, int i, int j){
  float ac2[4][4]={};
  for(int kc=0;kc<32;kc+=4){
    float a_[4][4], b_[4][4];
    #pragma unroll
    for(int e=0;e<4;e++)
      #pragma unroll
      for(int g=0;g<4;g++){
        a_[e][g]=W[(32*i+r0+e)*SA + 32*i+kc+g];
        b_[e][g]=T[(kc+e)*33 + c0+g];
      }
    #pragma unroll
    for(int e=0;e<4;e++)
      #pragma unroll
      for(int f=0;f<4;f++)
        ac2[e][f]+=a_[e][0]*b_[0][f]+a_[e][1]*b_[1][f]
                  +a_[e][2]*b_[2][f]+a_[e][3]*b_[3][f];
  }
  #pragma unroll
  for(int e=0;e<4;e++)
    #pragma unroll
    for(int f=0;f<4;f++)
      W[(32*i+r0+e)*SA+32*j+c0+f] = -ac2[e][f];
}

__device__ __forceinline__ void pack_tile(const float* __restrict__ W,
                                          uint4* __restrict__ uf4, int tile, int l){
  int db = (tile<2)?0:((tile<6)?1:((tile<12)?2:3));
  int kc = tile - ((db==0)?0:((db==1)?2:((db==2)?6:12)));
  int row=db*32+(l&31), colb=kc*16+((l>>5)<<3);
  unsigned uu[4];
  #pragma unroll
  for(int h2=0;h2<4;h2++){
    unsigned lo=f2bf(W[row*SA+colb+2*h2]);
    unsigned hi=f2bf(W[row*SA+colb+2*h2+1]);
    uu[h2]=lo|(hi<<16);
  }
  uint4 wv; wv.x=uu[0]; wv.y=uu[1]; wv.z=uu[2]; wv.w=uu[3];
  uf4[tile*64 + l] = wv;
}

// ---------------------------------------------------------------------------
// k_prep: EXACT R7-R10 version (~63 us steady).
// ---------------------------------------------------------------------------
__global__ __launch_bounds__(256) void k_prep(const float* __restrict__ cov,
                                              const float* __restrict__ wts,
                                              const float* __restrict__ means,
                                              float* __restrict__ ws_c3,
                                              unsigned short* __restrict__ qfrag,
                                              unsigned short* __restrict__ ufrag){
  __shared__ float A[DDIM*SA];
  __shared__ float W[DDIM*SA];
  __shared__ float Tb[3*1056];
  __shared__ float muS[DDIM];
  __shared__ float mq[256];
  const int t=threadIdx.x, w=t>>6, l=t&63, k=blockIdx.x;
  const int r0=(l>>3)*4, c0=(l&7)*4;
  uint4* ufK = (uint4*)ufrag + (size_t)k*UFT;

  const float4* cv4 = (const float4*)(cov + (size_t)k*DDIM*DDIM);
  #pragma unroll
  for(int v=0; v<16; v++){
    int idx4 = t + 256*v; float4 f = cv4[idx4];
    int e = idx4*4; int i = e>>7; int j = e&127;
    float* d = &A[i*SA+j]; d[0]=f.x; d[1]=f.y; d[2]=f.z; d[3]=f.w;
  }
  for(int z=t; z<DDIM*SA; z+=256) W[z] = 0.f;
  if(t<DDIM) muS[t] = means[k*DDIM+t];
  __syncthreads();
  if(t<DDIM) A[t*SA+t] += GMM_EPS;
  __syncthreads();

  float hl = 0.f;
  if(w==0) hl += chol_inv32(&A[0], &W[0], l&31);
  __syncthreads();
  if(w==1)      panel_unit(A,W,r0,c0,0,1);
  else if(w==2) panel_unit(A,W,r0,c0,0,2);
  else if(w==3) panel_unit(A,W,r0,c0,0,3);
  __syncthreads();
  if(w==0)      syrk_unit(A,r0,c0,0,1,1);
  else if(w==1) syrk_unit(A,r0,c0,0,2,1);
  else if(w==2) syrk_unit(A,r0,c0,0,3,1);
  else          syrk_unit(A,r0,c0,0,2,2);
  __syncthreads();
  if(w==0)      hl += chol_inv32(&A[32*SA+32], &W[32*SA+32], l&31);
  else if(w==1) syrk_unit(A,r0,c0,0,3,2);
  else if(w==2) syrk_unit(A,r0,c0,0,3,3);
  __syncthreads();
  if(w==1)      panel_unit(A,W,r0,c0,1,2);
  else if(w==2) panel_unit(A,W,r0,c0,1,3);
  else if(w==3) tg_unit(A,W,&Tb[0],r0,c0,1,0);
  __syncthreads();
  if(w==0)      syrk_unit(A,r0,c0,1,2,2);
  else if(w==1) a2_unit(W,&Tb[0],r0,c0,1,0);
  else if(w==2) tg_unit(A,W,&Tb[1056],r0,c0,2,1);
  else          syrk_unit(A,r0,c0,1,3,2);
  __syncthreads();
  if(w==0)      hl += chol_inv32(&A[64*SA+64], &W[64*SA+64], l&31);
  else if(w==1) syrk_unit(A,r0,c0,1,3,3);
  else if(w==2) tg_unit(A,W,&Tb[0],r0,c0,2,0);
  __syncthreads();
  if(w==1)      panel_unit(A,W,r0,c0,2,3);
  else if(w==2) a2_unit(W,&Tb[0],r0,c0,2,0);
  else if(w==3) a2_unit(W,&Tb[1056],r0,c0,2,1);
  __syncthreads();
  if(w==0)      syrk_unit(A,r0,c0,2,3,3);
  else if(w==1) tg_unit(A,W,&Tb[0],r0,c0,3,0);
  else if(w==2) tg_unit(A,W,&Tb[1056],r0,c0,3,1);
  else          tg_unit(A,W,&Tb[2112],r0,c0,3,2);
  __syncthreads();
  if(w==0)      hl += chol_inv32(&A[96*SA+96], &W[96*SA+96], l&31);
  else if(w==1 || (w==2 && l<32)){
    int r = (w==1)? l : 64+l;
    float s=0.f;
    #pragma unroll 8
    for(int c=0;c<DDIM;c++) s += W[r*SA+c]*muS[c];
    mq[r]=s;
  }
  __syncthreads();
  if(w==1)      a2_unit(W,&Tb[0],r0,c0,3,0);
  else if(w==2) a2_unit(W,&Tb[1056],r0,c0,3,1);
  else if(w==3) a2_unit(W,&Tb[2112],r0,c0,3,2);
  __syncthreads();
  if(w==0){
    if(l<32){
      int r = 96+l;
      float s=0.f;
      #pragma unroll 8
      for(int c=0;c<DDIM;c++) s += W[r*SA+c]*muS[c];
      mq[r]=s;
    }
  } else {
    #pragma unroll
    for(int j=0;j<4;j++) pack_tile(W, ufK, (w-1)*4+j, l);
  }
  __syncthreads();
  if(t<128){
    float s=0.f;
    #pragma unroll 8
    for(int r=0;r<DDIM;r++) s += W[r*SA+t]*mq[r];
    mq[128+t]=s;
  } else if(w==2){
    #pragma unroll
    for(int j=0;j<4;j++) pack_tile(W, ufK, 12+j, l);
  } else {
    #pragma unroll
    for(int j=0;j<4;j++) pack_tile(W, ufK, 16+j, l);
  }
  __syncthreads();
  if(w==0){
    float hv = (l<32)? hl : 0.f;
    float p  = mq[l]*mq[l] + mq[l+64]*mq[l+64];
    #pragma unroll
    for(int off=32; off; off>>=1){ hv += __shfl_xor(hv,off); p += __shfl_xor(p,off); }
    if(l==0) ws_c3[k] = logf(wts[k]) - hv - 117.6241322f - 0.5f*p;
  } else if(w==1 && l<16){
    int tile=l>>1, half=l&1;
    const float* qq=&mq[128 + tile*16 + half*8];
    unsigned uu[4];
    #pragma unroll
    for(int h2=0;h2<4;h2++){
      unsigned lo=f2bf(qq[2*h2]), hi=f2bf(qq[2*h2+1]);
      uu[h2]=lo|(hi<<16);
    }
    uint4 wv; wv.x=uu[0]; wv.y=uu[1]; wv.z=uu[2]; wv.w=uu[3];
    ((uint4*)qfrag)[tile*64 + half*32 + k] = wv;
  }
}

// ---------------------------------------------------------------------------
// k_main (R13 = R12 resubmit; container flake suspected): R10 structure +
// asm-pinned U registers. R9's VGPR_Count=96 proved the compiler sinks the
// ur[20] loads into the tile loop (U re-fetched 4x per comp from L2
// ~1.3 GB/launch — the R4-R11 plateau). One asm pin per uint4 makes the
// loaded values opaque asm outputs: no rematerialization, all 80 VGPRs
// stay live (~190 total < 256 cap, no spill). U L2 traffic drops 4x.
// ---------------------------------------------------------------------------
#define MFMA_B(acc,u,xv) acc=__builtin_amdgcn_mfma_f32_32x32x16_bf16(__builtin_bit_cast(bf16x8,u),xv,acc,0,0,0)

__global__ __launch_bounds__(512,1) void k_main(const float* __restrict__ x,
                                                const uint4* __restrict__ uf,
                                                const uint4* __restrict__ qf,
                                                const float* __restrict__ ws_c3,
                                                float* __restrict__ out){
  __shared__ uint4 xs[4*8*64];       // 32 KB: x bf16 frags [tile][c][lane]
  __shared__ float lin[KCOMP*128];   // 16 KB: -2 q.x [comp][pt]
  __shared__ float mahaS[4*8*128];   // 16 KB: ||Ux||^2 [iter][wave][pt]
  __shared__ float c3s[KCOMP];
  const int t=threadIdx.x, lane=t&63, w=t>>6;
  const int qh=lane>>5, ln=lane&31;
  const size_t n0=(size_t)blockIdx.x*128;

  if(t<KCOMP) c3s[t]=ws_c3[t];

  // ---- stage 128 points of x -> bf16 frag layout in LDS (once) ----
  {
    const float* xb = x + n0*DDIM;
    #pragma unroll
    for(int j=0;j<8;j++){
      int idx = j*512 + t;
      int n = idx & 127, d0 = (idx>>7)*4;
      float4 f = *(const float4*)(xb + (size_t)n*DDIM + d0);
      unsigned lo = f2bf(f.x) | (((unsigned)f2bf(f.y))<<16);
      unsigned hi = f2bf(f.z) | (((unsigned)f2bf(f.w))<<16);
      int tile=n>>5, lnn=n&31, c=d0>>4, qq=(d0>>3)&1, e4=d0&7;
      *(uint2*)((char*)xs + tile*8192 + c*1024 + qq*512 + lnn*16 + e4*2)
          = make_uint2(lo,hi);
    }
  }
  __syncthreads();   // barrier #1: xs ready (also covers c3s)

  // ---- prologue: lin[k][pt] = -2 q_k . x_pt (waves 0-3, tile = w) ----
  if(w<4){
    f32x16 aq={};
    #pragma unroll
    for(int c=0;c<8;c++){
      uint4 qr = qf[c*64+lane];
      bf16x8 xq = __builtin_bit_cast(bf16x8, xs[w*512 + c*64 + lane]);
      MFMA_B(aq, qr, xq);
    }
    #pragma unroll
    for(int r=0;r<16;r++){
      int row=(r&3)+8*(r>>2)+4*qh;       // row = comp (validated C-layout)
      lin[row*128 + w*32 + ln] = -2.f*aq[r];
    }
  }

  // ---- comp loop: NO barriers. Each (iter,wave) owns mahaS slot. ----
  #pragma unroll 1
  for(int iter=0;iter<4;iter++){
    const int k = iter*8 + w;
    uint4 ur[20];
    #pragma unroll
    for(int j=0;j<20;j++){
      ur[j]=uf[(size_t)k*UFT + j*64 + lane];
      // PIN: loaded value becomes an opaque asm output — the allocator
      // cannot sink/rematerialize the load inside the tile loop.
      asm volatile("" : "+v"(ur[j].x), "+v"(ur[j].y), "+v"(ur[j].z), "+v"(ur[j].w));
    }

    #pragma unroll 1
    for(int tile=0;tile<4;tile++){
      bf16x8 xf[8];
      #pragma unroll
      for(int c=0;c<8;c++) xf[c]=__builtin_bit_cast(bf16x8, xs[tile*512 + c*64 + lane]);
      f32x16 a0={},a1={},a2={},a3={};
      #pragma unroll
      for(int c=0;c<2;c++) MFMA_B(a0, ur[c],    xf[c]);   // db0: kc 0..1
      #pragma unroll
      for(int c=0;c<4;c++) MFMA_B(a1, ur[2+c],  xf[c]);   // db1: kc 0..3
      #pragma unroll
      for(int c=0;c<6;c++) MFMA_B(a2, ur[6+c],  xf[c]);   // db2: kc 0..5
      #pragma unroll
      for(int c=0;c<8;c++) MFMA_B(a3, ur[12+c], xf[c]);   // db3: kc 0..7
      float p0=0.f,p1=0.f,p2=0.f,p3=0.f;
      #pragma unroll
      for(int r=0;r<16;r+=2){
        p0=fmaf(a0[r],a0[r],p0); p1=fmaf(a0[r+1],a0[r+1],p1);
        p2=fmaf(a1[r],a1[r],p2); p3=fmaf(a1[r+1],a1[r+1],p3);
        p0=fmaf(a2[r],a2[r],p0); p1=fmaf(a2[r+1],a2[r+1],p1);
        p2=fmaf(a3[r],a3[r],p2); p3=fmaf(a3[r+1],a3[r+1],p3);
      }
      float p=(p0+p1)+(p2+p3);
      p += __shfl_xor(p,32);             // fold qh halves (other 16 rows/db)
      if(qh==0) mahaS[iter*1024 + w*128 + tile*32 + ln] = p;
    }
  }
  __syncthreads();   // barrier #2: all mahaS + lin ready

  // ---- single logsumexp epilogue over all 32 comps ----
  if(t<128){
    float m_run=-INFINITY, s_run=0.f;
    #pragma unroll 1
    for(int k3=0;k3<KCOMP;k3++){
      float a  = c3s[k3] - 0.5f*(mahaS[(k3>>3)*1024 + (k3&7)*128 + t] + lin[k3*128 + t]);
      float nm = fmaxf(m_run,a);
      s_run = s_run*__expf(m_run-nm)+__expf(a-nm);
      m_run = nm;
    }
    out[n0+t] = m_run + logf(s_run);
  }
}

// ---------------------------------------------------------------------------
extern "C" void kernel_launch(void* const* d_in, const int* in_sizes, int n_in,
                              void* d_out, int out_size, void* d_ws, size_t ws_size,
                              hipStream_t stream){
  const float* x   = (const float*)d_in[0];
  const float* mu  = (const float*)d_in[1];
  const float* cov = (const float*)d_in[2];
  const float* wts = (const float*)d_in[3];
  float* out = (float*)d_out;
  char*  ws  = (char*)d_ws;

  float*          wsC3 = (float*)ws;                    // 128 B (c3)
  unsigned short* wsQF = (unsigned short*)(ws + 512);   // 8 KB (Q bf16 frags)
  unsigned short* wsUF = (unsigned short*)(ws + 16384); // 640 KB (U bf16 frags, tight)

  k_prep<<<KCOMP, 256, 0, stream>>>(cov, wts, mu, wsC3, wsQF, wsUF);
  k_main<<<NPTS/128, 512, 0, stream>>>(x, (const uint4*)wsUF, (const uint4*)wsQF, wsC3, out);
}

// Round 14
// 172.038 us; speedup vs baseline: 1.1964x; 1.1964x over previous
//
#include <hip/hip_runtime.h>
#include <hip/hip_bf16.h>
#include <math.h>

#define KCOMP 32
#define DDIM  128
#define NPTS  65536
#define GMM_EPS 1e-6f
#define SA 129   // LDS row stride (odd -> conflict-free for scalar col access)
#define UFT 1280 // uint4 per component: 20 nonzero (db,kc) tiles * 64 lanes

typedef __attribute__((ext_vector_type(8)))  __bf16 bf16x8;
typedef __attribute__((ext_vector_type(16))) float  f32x16;

__device__ __forceinline__ unsigned short f2bf(float f){
  unsigned u = __builtin_bit_cast(unsigned, f);
  u = (u + 0x7FFFu + ((u >> 16) & 1u)) >> 16;   // RNE
  return (unsigned short)u;
}
__device__ __forceinline__ float rlane(float v, int lsrc){
  return __builtin_bit_cast(float, __builtin_amdgcn_readlane(__builtin_bit_cast(int, v), lsrc));
}

// ---------------------------------------------------------------------------
// chol_inv32 (R6, validated): register Cholesky + triangular inverse, 32x32.
// logf off the pivot chain; right-looking forward substitution.
// ---------------------------------------------------------------------------
__device__ __noinline__ float chol_inv32(float* __restrict__ Ab,
                                         float* __restrict__ Wb,
                                         const int c){
  float ar[32], lr[32], rd[32], s[32];
  #pragma unroll
  for(int i=0;i<32;i++) ar[i] = Ab[i*SA + c];
  float mydiag = 1.f;
  #pragma unroll
  for(int j=0;j<32;j++){
    float d   = rlane(ar[j], j);
    float rsd = rsqrtf(d);
    rd[j] = rsd;
    float Lcj  = ar[j]*rsd;
    lr[j] = (c>=j) ? Lcj : 0.f;
    if(c==j) mydiag = Lcj;              // = sqrt(d), off critical path
    float coef = Lcj*rsd;
    #pragma unroll
    for(int i=j+1;i<32;i++){
      float bij = rlane(ar[i], j);
      ar[i] = fmaf(-bij, coef, ar[i]);
    }
  }
  #pragma unroll
  for(int j=0;j<32;j++) Ab[c*SA + j] = lr[j];
  #pragma unroll
  for(int i=0;i<32;i++) s[i] = (i==c) ? 1.f : 0.f;
  #pragma unroll
  for(int j=0;j<32;j++){
    float vj = s[j]*rd[j];
    s[j] = vj;
    #pragma unroll
    for(int i=j+1;i<32;i++)
      s[i] = fmaf(-rlane(lr[j], i), vj, s[i]);
  }
  #pragma unroll
  for(int i=0;i<32;i++) Wb[i*SA + c] = s[i];
  return logf(mydiag);
}

// ---- GEMM unit bodies: R6-exact (forceinline), byte-identical math ----
__device__ __forceinline__ void panel_unit(float* __restrict__ A, const float* __restrict__ W,
                                           int r0, int c0, int b, int ibl){
  const int b32=b*32;
  float acc[4][4]={};
  for(int kc=0;kc<32;kc+=4){
    float a_[4][4], b_[4][4];
    #pragma unroll
    for(int e=0;e<4;e++)
      #pragma unroll
      for(int g=0;g<4;g++){
        a_[e][g]=A[(32*ibl+r0+e)*SA + b32+kc+g];
        b_[e][g]=W[(b32+c0+e)*SA   + b32+kc+g];
      }
    #pragma unroll
    for(int e=0;e<4;e++)
      #pragma unroll
      for(int f=0;f<4;f++)
        acc[e][f]+=a_[e][0]*b_[f][0]+a_[e][1]*b_[f][1]
                  +a_[e][2]*b_[f][2]+a_[e][3]*b_[f][3];
  }
  #pragma unroll
  for(int e=0;e<4;e++)
    #pragma unroll
    for(int f=0;f<4;f++)
      A[(32*ibl+r0+e)*SA + b32+c0+f] = acc[e][f];
}

__device__ __forceinline__ void syrk_unit(float* __restrict__ A,
                                          int r0, int c0, int b, int ui, int uj){
  const int b32=b*32;
  float acc[4][4]={};
  for(int kc=0;kc<32;kc+=4){
    float a_[4][4], b_[4][4];
    #pragma unroll
    for(int e=0;e<4;e++)
      #pragma unroll
      for(int g=0;g<4;g++){
        a_[e][g]=A[(32*ui+r0+e)*SA + b32+kc+g];
        b_[e][g]=A[(32*uj+c0+e)*SA + b32+kc+g];
      }
    #pragma unroll
    for(int e=0;e<4;e++)
      #pragma unroll
      for(int f=0;f<4;f++)
        acc[e][f]+=a_[e][0]*b_[f][0]+a_[e][1]*b_[f][1]
                  +a_[e][2]*b_[f][2]+a_[e][3]*b_[f][3];
  }
  #pragma unroll
  for(int e=0;e<4;e++)
    #pragma unroll
    for(int f=0;f<4;f++)
      A[(32*ui+r0+e)*SA+32*uj+c0+f] -= acc[e][f];
}

__device__ __forceinline__ void tg_unit(const float* __restrict__ A, const float* __restrict__ W,
                                        float* __restrict__ T, int r0, int c0, int i, int j){
  float acc[4][4]={};
  #pragma unroll 1
  for(int p=j;p<i;p++){
    for(int kc=0;kc<32;kc+=4){
      float a_[4][4], b_[4][4];
      #pragma unroll
      for(int e=0;e<4;e++)
        #pragma unroll
        for(int g=0;g<4;g++){
          a_[e][g]=A[(32*i+r0+e)*SA + 32*p+kc+g];
          b_[e][g]=W[(32*p+kc+e)*SA + 32*j+c0+g];
        }
      #pragma unroll
      for(int e=0;e<4;e++)
        #pragma unroll
        for(int f=0;f<4;f++)
          acc[e][f]+=a_[e][0]*b_[0][f]+a_[e][1]*b_[1][f]
                    +a_[e][2]*b_[2][f]+a_[e][3]*b_[3][f];
    }
  }
  #pragma unroll
  for(int e=0;e<4;e++)
    #pragma unroll
    for(int f=0;f<4;f++)
      T[(r0+e)*33+c0+f]=acc[e][f];
}

__device__ __forceinline__ void a2_unit(float* __restrict__ W, const float* __restrict__ T,
                                        int r0, int c0, int i, int j){
  float ac2[4][4]={};
  for(int kc=0;kc<32;kc+=4){
    float a_[4][4], b_[4][4];
    #pragma unroll
    for(int e=0;e<4;e++)
      #pragma unroll
      for(int g=0;g<4;g++){
        a_[e][g]=W[(32*i+r0+e)*SA + 32*i+kc+g];
        b_[e][g]=T[(kc+e)*33 + c0+g];
      }
    #pragma unroll
    for(int e=0;e<4;e++)
      #pragma unroll
      for(int f=0;f<4;f++)
        ac2[e][f]+=a_[e][0]*b_[0][f]+a_[e][1]*b_[1][f]
                  +a_[e][2]*b_[2][f]+a_[e][3]*b_[3][f];
  }
  #pragma unroll
  for(int e=0;e<4;e++)
    #pragma unroll
    for(int f=0;f<4;f++)
      W[(32*i+r0+e)*SA+32*j+c0+f] = -ac2[e][f];
}

__device__ __forceinline__ void pack_tile(const float* __restrict__ W,
                                          uint4* __restrict__ uf4, int tile, int l){
  int db = (tile<2)?0:((tile<6)?1:((tile<12)?2:3));
  int kc = tile - ((db==0)?0:((db==1)?2:((db==2)?6:12)));
  int row=db*32+(l&31), colb=kc*16+((l>>5)<<3);
  unsigned uu[4];
  #pragma unroll
  for(int h2=0;h2<4;h2++){
    unsigned lo=f2bf(W[row*SA+colb+2*h2]);
    unsigned hi=f2bf(W[row*SA+colb+2*h2+1]);
    uu[h2]=lo|(hi<<16);
  }
  uint4 wv; wv.x=uu[0]; wv.y=uu[1]; wv.z=uu[2]; wv.w=uu[3];
  uf4[tile*64 + l] = wv;
}

// ---------------------------------------------------------------------------
// k_prep (R6-exact DAG schedule, measured 62 us steady / 171.3 total).
// ---------------------------------------------------------------------------
__global__ __launch_bounds__(256) void k_prep(const float* __restrict__ cov,
                                              const float* __restrict__ wts,
                                              const float* __restrict__ means,
                                              float* __restrict__ ws_c3,
                                              unsigned short* __restrict__ qfrag,
                                              unsigned short* __restrict__ ufrag){
  __shared__ float A[DDIM*SA];      // 64.5 KB: cov -> L (lower)
  __shared__ float W[DDIM*SA];      // 64.5 KB: U = L^{-1} (lower), 0 above
  __shared__ float Tb[3*1056];      // 12.4 KB: T slots, slot j for T_{i,j}
  __shared__ float muS[DDIM];
  __shared__ float mq[256];         // m' [0..127], q [128..255]
  const int t=threadIdx.x, w=t>>6, l=t&63, k=blockIdx.x;
  const int r0=(l>>3)*4, c0=(l&7)*4;
  uint4* ufK = (uint4*)ufrag + (size_t)k*UFT;

  // Ph0: load cov->A, zero W, stage mu
  const float4* cv4 = (const float4*)(cov + (size_t)k*DDIM*DDIM);
  #pragma unroll
  for(int v=0; v<16; v++){
    int idx4 = t + 256*v; float4 f = cv4[idx4];
    int e = idx4*4; int i = e>>7; int j = e&127;
    float* d = &A[i*SA+j]; d[0]=f.x; d[1]=f.y; d[2]=f.z; d[3]=f.w;
  }
  for(int z=t; z<DDIM*SA; z+=256) W[z] = 0.f;
  if(t<DDIM) muS[t] = means[k*DDIM+t];
  __syncthreads();
  if(t<DDIM) A[t*SA+t] += GMM_EPS;
  __syncthreads();

  float hl = 0.f;
  // Ph1: C0
  if(w==0) hl += chol_inv32(&A[0], &W[0], l&31);
  __syncthreads();
  // Ph2: P0 (ibl=1,2,3)
  if(w==1)      panel_unit(A,W,r0,c0,0,1);
  else if(w==2) panel_unit(A,W,r0,c0,0,2);
  else if(w==3) panel_unit(A,W,r0,c0,0,3);
  __syncthreads();
  // Ph3: S0 diag (1,1) + S0 rest starts
  if(w==0)      syrk_unit(A,r0,c0,0,1,1);
  else if(w==1) syrk_unit(A,r0,c0,0,2,1);
  else if(w==2) syrk_unit(A,r0,c0,0,3,1);
  else          syrk_unit(A,r0,c0,0,2,2);
  __syncthreads();
  // Ph4: C1 || S0 rest
  if(w==0)      hl += chol_inv32(&A[32*SA+32], &W[32*SA+32], l&31);
  else if(w==1) syrk_unit(A,r0,c0,0,3,2);
  else if(w==2) syrk_unit(A,r0,c0,0,3,3);
  __syncthreads();
  // Ph5: P1 (ibl=2,3) + T_10
  if(w==1)      panel_unit(A,W,r0,c0,1,2);
  else if(w==2) panel_unit(A,W,r0,c0,1,3);
  else if(w==3) tg_unit(A,W,&Tb[0],r0,c0,1,0);
  __syncthreads();
  // Ph6: S1 diag (2,2) + A2_10 + T_21 + S1(3,2)
  if(w==0)      syrk_unit(A,r0,c0,1,2,2);
  else if(w==1) a2_unit(W,&Tb[0],r0,c0,1,0);
  else if(w==2) tg_unit(A,W,&Tb[1056],r0,c0,2,1);
  else          syrk_unit(A,r0,c0,1,3,2);
  __syncthreads();
  // Ph7: C2 || S1(3,3) + T_20 (K=64)
  if(w==0)      hl += chol_inv32(&A[64*SA+64], &W[64*SA+64], l&31);
  else if(w==1) syrk_unit(A,r0,c0,1,3,3);
  else if(w==2) tg_unit(A,W,&Tb[0],r0,c0,2,0);
  __syncthreads();
  // Ph8: P2 (ibl=3) + A2_20 + A2_21
  if(w==1)      panel_unit(A,W,r0,c0,2,3);
  else if(w==2) a2_unit(W,&Tb[0],r0,c0,2,0);
  else if(w==3) a2_unit(W,&Tb[1056],r0,c0,2,1);
  __syncthreads();
  // Ph9: S2 diag (3,3) + T_30 (K=96) + T_31 (K=64) + T_32 (K=32)
  if(w==0)      syrk_unit(A,r0,c0,2,3,3);
  else if(w==1) tg_unit(A,W,&Tb[0],r0,c0,3,0);
  else if(w==2) tg_unit(A,W,&Tb[1056],r0,c0,3,1);
  else          tg_unit(A,W,&Tb[2112],r0,c0,3,2);
  __syncthreads();
  // Ph10: C3 || m' rows 0-95 (W block-rows 0-2 final since Ph8)
  if(w==0)      hl += chol_inv32(&A[96*SA+96], &W[96*SA+96], l&31);
  else if(w==1 || (w==2 && l<32)){
    int r = (w==1)? l : 64+l;
    float s=0.f;
    #pragma unroll 8
    for(int c=0;c<DDIM;c++) s += W[r*SA+c]*muS[c];
    mq[r]=s;
  }
  __syncthreads();
  // Ph11: A2_30 + A2_31 + A2_32
  if(w==1)      a2_unit(W,&Tb[0],r0,c0,3,0);
  else if(w==2) a2_unit(W,&Tb[1056],r0,c0,3,1);
  else if(w==3) a2_unit(W,&Tb[2112],r0,c0,3,2);
  __syncthreads();
  // Ph12: m' rows 96-127 (w0) + pack U tiles 0-11 (db 0-2, final since Ph8)
  if(w==0){
    if(l<32){
      int r = 96+l;
      float s=0.f;
      #pragma unroll 8
      for(int c=0;c<DDIM;c++) s += W[r*SA+c]*muS[c];
      mq[r]=s;
    }
  } else {
    #pragma unroll
    for(int j=0;j<4;j++) pack_tile(W, ufK, (w-1)*4+j, l);
  }
  __syncthreads();
  // Ph13: q = U^T m' (t<128) + pack U tiles 12-19 (db 3, final since Ph11)
  if(t<128){
    float s=0.f;
    #pragma unroll 8
    for(int r=0;r<DDIM;r++) s += W[r*SA+t]*mq[r];
    mq[128+t]=s;
  } else if(w==2){
    #pragma unroll
    for(int j=0;j<4;j++) pack_tile(W, ufK, 12+j, l);
  } else {
    #pragma unroll
    for(int j=0;j<4;j++) pack_tile(W, ufK, 16+j, l);
  }
  __syncthreads();
  // Ph14: c3 (w0: ||m'||^2 + logdet lane-reduce) + qfrag (w1)
  if(w==0){
    float hv = (l<32)? hl : 0.f;          // lanes 32-63 hold duplicate chol
    float p  = mq[l]*mq[l] + mq[l+64]*mq[l+64];
    #pragma unroll
    for(int off=32; off; off>>=1){ hv += __shfl_xor(hv,off); p += __shfl_xor(p,off); }
    if(l==0) ws_c3[k] = logf(wts[k]) - hv - 117.6241322f - 0.5f*p;
  } else if(w==1 && l<16){
    int tile=l>>1, half=l&1;
    const float* qq=&mq[128 + tile*16 + half*8];
    unsigned uu[4];
    #pragma unroll
    for(int h2=0;h2<4;h2++){
      unsigned lo=f2bf(qq[2*h2]), hi=f2bf(qq[2*h2+1]);
      uu[h2]=lo|(hi<<16);
    }
    uint4 wv; wv.x=uu[0]; wv.y=uu[1]; wv.z=uu[2]; wv.w=uu[3];
    ((uint4*)qfrag)[tile*64 + half*32 + k] = wv;
  }
}

// ---------------------------------------------------------------------------
// k_main (R5/R6-exact, no pins): barrier-free comp loop, 512 thr = 8 waves,
// 128 points staged once in LDS, wave w sweeps comps {w,w+8,w+16,w+24}.
// The pin experiment (R12/R13) regressed +31 us: volatile asm serialized
// the 20 loads per iter and VGPR 96->~200 halved blocks/CU — the compiler's
// streamed 96-VGPR form + 2 blocks/CU is the best-measured configuration.
// ---------------------------------------------------------------------------
#define MFMA_B(acc,u,xv) acc=__builtin_amdgcn_mfma_f32_32x32x16_bf16(__builtin_bit_cast(bf16x8,u),xv,acc,0,0,0)

__global__ __launch_bounds__(512,2) void k_main(const float* __restrict__ x,
                                                const uint4* __restrict__ uf,
                                                const uint4* __restrict__ qf,
                                                const float* __restrict__ ws_c3,
                                                float* __restrict__ out){
  __shared__ uint4 xs[4*8*64];       // 32 KB: x bf16 frags [tile][c][lane]
  __shared__ float lin[KCOMP*128];   // 16 KB: -2 q.x [comp][pt]
  __shared__ float mahaS[4*8*128];   // 16 KB: ||Ux||^2 [iter][wave][pt]
  __shared__ float c3s[KCOMP];
  const int t=threadIdx.x, lane=t&63, w=t>>6;
  const int qh=lane>>5, ln=lane&31;
  const size_t n0=(size_t)blockIdx.x*128;

  if(t<KCOMP) c3s[t]=ws_c3[t];

  // ---- stage 128 points of x -> bf16 frag layout in LDS (once) ----
  {
    const float* xb = x + n0*DDIM;
    #pragma unroll
    for(int j=0;j<8;j++){
      int idx = j*512 + t;
      int n = idx & 127, d0 = (idx>>7)*4;
      float4 f = *(const float4*)(xb + (size_t)n*DDIM + d0);
      unsigned lo = f2bf(f.x) | (((unsigned)f2bf(f.y))<<16);
      unsigned hi = f2bf(f.z) | (((unsigned)f2bf(f.w))<<16);
      int tile=n>>5, lnn=n&31, c=d0>>4, qq=(d0>>3)&1, e4=d0&7;
      *(uint2*)((char*)xs + tile*8192 + c*1024 + qq*512 + lnn*16 + e4*2)
          = make_uint2(lo,hi);
    }
  }
  __syncthreads();   // barrier #1: xs ready (also covers c3s)

  // ---- prologue: lin[k][pt] = -2 q_k . x_pt (waves 0-3, tile = w) ----
  if(w<4){
    f32x16 aq={};
    #pragma unroll
    for(int c=0;c<8;c++){
      uint4 qr = qf[c*64+lane];
      bf16x8 xq = __builtin_bit_cast(bf16x8, xs[w*512 + c*64 + lane]);
      MFMA_B(aq, qr, xq);
    }
    #pragma unroll
    for(int r=0;r<16;r++){
      int row=(r&3)+8*(r>>2)+4*qh;       // row = comp (validated C-layout)
      lin[row*128 + w*32 + ln] = -2.f*aq[r];
    }
  }

  // ---- comp loop: NO barriers. Each (iter,wave) owns mahaS slot. ----
  #pragma unroll 1
  for(int iter=0;iter<4;iter++){
    const int k = iter*8 + w;
    uint4 ur[20];
    #pragma unroll
    for(int j=0;j<20;j++) ur[j]=uf[(size_t)k*UFT + j*64 + lane];

    #pragma unroll 1
    for(int tile=0;tile<4;tile++){
      bf16x8 xf[8];
      #pragma unroll
      for(int c=0;c<8;c++) xf[c]=__builtin_bit_cast(bf16x8, xs[tile*512 + c*64 + lane]);
      f32x16 a0={},a1={},a2={},a3={};
      #pragma unroll
      for(int c=0;c<2;c++) MFMA_B(a0, ur[c],    xf[c]);   // db0: kc 0..1
      #pragma unroll
      for(int c=0;c<4;c++) MFMA_B(a1, ur[2+c],  xf[c]);   // db1: kc 0..3
      #pragma unroll
      for(int c=0;c<6;c++) MFMA_B(a2, ur[6+c],  xf[c]);   // db2: kc 0..5
      #pragma unroll
      for(int c=0;c<8;c++) MFMA_B(a3, ur[12+c], xf[c]);   // db3: kc 0..7
      float p0=0.f,p1=0.f,p2=0.f,p3=0.f;
      #pragma unroll
      for(int r=0;r<16;r+=2){
        p0=fmaf(a0[r],a0[r],p0); p1=fmaf(a0[r+1],a0[r+1],p1);
        p2=fmaf(a1[r],a1[r],p2); p3=fmaf(a1[r+1],a1[r+1],p3);
        p0=fmaf(a2[r],a2[r],p0); p1=fmaf(a2[r+1],a2[r+1],p1);
        p2=fmaf(a3[r],a3[r],p2); p3=fmaf(a3[r+1],a3[r+1],p3);
      }
      float p=(p0+p1)+(p2+p3);
      p += __shfl_xor(p,32);             // fold qh halves (other 16 rows/db)
      if(qh==0) mahaS[iter*1024 + w*128 + tile*32 + ln] = p;
    }
  }
  __syncthreads();   // barrier #2: all mahaS + lin ready

  // ---- single logsumexp epilogue over all 32 comps ----
  if(t<128){
    float m_run=-INFINITY, s_run=0.f;
    #pragma unroll 1
    for(int k3=0;k3<KCOMP;k3++){
      float a  = c3s[k3] - 0.5f*(mahaS[(k3>>3)*1024 + (k3&7)*128 + t] + lin[k3*128 + t]);
      float nm = fmaxf(m_run,a);
      s_run = s_run*__expf(m_run-nm)+__expf(a-nm);
      m_run = nm;
    }
    out[n0+t] = m_run + logf(s_run);
  }
}

// ---------------------------------------------------------------------------
extern "C" void kernel_launch(void* const* d_in, const int* in_sizes, int n_in,
                              void* d_out, int out_size, void* d_ws, size_t ws_size,
                              hipStream_t stream){
  const float* x   = (const float*)d_in[0];
  const float* mu  = (const float*)d_in[1];
  const float* cov = (const float*)d_in[2];
  const float* wts = (const float*)d_in[3];
  float* out = (float*)d_out;
  char*  ws  = (char*)d_ws;

  float*          wsC3 = (float*)ws;                    // 128 B (c3)
  unsigned short* wsQF = (unsigned short*)(ws + 512);   // 8 KB (Q bf16 frags)
  unsigned short* wsUF = (unsigned short*)(ws + 16384); // 640 KB (U bf16 frags, tight)

  k_prep<<<KCOMP, 256, 0, stream>>>(cov, wts, mu, wsC3, wsQF, wsUF);
  k_main<<<NPTS/128, 512, 0, stream>>>(x, (const uint4*)wsUF, (const uint4*)wsQF, wsC3, out);
}